// Round 6
// baseline (55.610 us; speedup 1.0000x reference)
//
#include <hip/hip_runtime.h>
#include <math.h>

#define TPB 256
#define NC 21   // classes
#define NM 32   // targets per image

// ---------------- main per-anchor kernel ----------------
__global__ __launch_bounds__(TPB) void detloss_main(
    const float* __restrict__ cls, const float* __restrict__ reg,
    const float* __restrict__ tbx, const int* __restrict__ tlb,
    float* __restrict__ partials, int N, int nblk)
{
    __shared__ float4 s_tb4[NM];
    __shared__ float  s_area2[NM];
    __shared__ int    s_tl[NM];
    __shared__ float  s_cls[TPB * NC];   // 21504 B, stride 21 dwords (gcd(21,32)=1 -> 2-way max)
    __shared__ float  s_red[TPB / 64][5];

    const int t    = threadIdx.x;
    const int blk  = blockIdx.x;
    const int b    = blockIdx.y;
    const int row0 = blk * TPB;
    const int row  = row0 + t;

    // targets: one thread per target box
    if (t < NM) {
        const float4 tb = ((const float4*)tbx)[(size_t)b * NM + t];
        s_tb4[t]   = tb;
        s_area2[t] = (tb.z - tb.x) * (tb.w - tb.y);
        s_tl[t]    = tlb[(size_t)b * NM + t];
    }

    // ---- stage cls tile to REGISTERS with fully-coalesced float4 loads.
    // (84B-stride direct row reads cost ~6x L1-line amplification; coalesced
    // staging touches each 64B line once.) Loads issue here, are consumed
    // after the IoU loop -> HBM latency hides under IoU VALU work.
    const int rows = min(TPB, N - row0);
    const float* cls_base = cls + ((size_t)b * N + row0) * NC;
    const bool fastpath = (rows == TPB) && ((((size_t)cls_base) & 15) == 0);
    float4 stg[6];
    const int total4 = TPB * NC / 4;     // 1344
    if (fastpath) {
        const float4* s4 = (const float4*)cls_base;
        #pragma unroll
        for (int r = 0; r < 6; ++r) {
            const int i = r * TPB + t;
            if (i < total4) stg[r] = s4[i];
        }
    }

    // per-thread anchor box (coalesced float4), clamped
    const int   rowi = (row < N) ? row : (N - 1);
    const float msk  = (row < N) ? 1.f : 0.f;
    const float4 rg  = ((const float4*)reg)[(size_t)b * N + rowi];

    __syncthreads();   // targets ready

    // ---- divide-free argmax-IoU (VALU only; covers staging-load latency).
    // unions strictly positive -> iou_j > iou_best <=> inter*bu > bi*uni
    const float a1 = (rg.z - rg.x) * (rg.w - rg.y);
    float bi, bu; int bidx = 0;
    {
        const float4 tb = s_tb4[0];
        const float lx = fmaxf(rg.x, tb.x), ly = fmaxf(rg.y, tb.y);
        const float rx = fminf(rg.z, tb.z), ry = fminf(rg.w, tb.w);
        const float w  = fmaxf(rx - lx, 0.f), h = fmaxf(ry - ly, 0.f);
        bi = w * h;
        bu = a1 + s_area2[0] - bi;
    }
    #pragma unroll
    for (int j = 1; j < NM; ++j) {
        const float4 tb = s_tb4[j];
        const float lx = fmaxf(rg.x, tb.x), ly = fmaxf(rg.y, tb.y);
        const float rx = fminf(rg.z, tb.z), ry = fminf(rg.w, tb.w);
        const float w  = fmaxf(rx - lx, 0.f), h = fmaxf(ry - ly, 0.f);
        const float inter = w * h;
        const float uni   = a1 + s_area2[j] - inter;
        const bool  gt    = inter * bu > bi * uni;   // strict > == first argmax
        bi   = gt ? inter : bi;
        bu   = gt ? uni   : bu;
        bidx = gt ? j     : bidx;
    }
    const bool pos = (bi >= 0.5f * bu);
    const bool neg = (bi <  0.3f * bu);
    const int  lbl = s_tl[bidx];

    // ---- write staged tile to LDS, then per-row reads (2-way conflicts max)
    if (fastpath) {
        float4* d4 = (float4*)s_cls;
        #pragma unroll
        for (int r = 0; r < 6; ++r) {
            const int i = r * TPB + t;
            if (i < total4) d4[i] = stg[r];
        }
    } else {
        for (int i = t; i < TPB * NC; i += TPB)
            s_cls[i] = (i < rows * NC) ? cls_base[i] : 0.f;
    }
    __syncthreads();

    // ---- log-sum-exp from LDS row. Native trans, no max-subtract
    // (inputs ~N(0,1), overflow-safe). xlbl = one dynamic LDS read.
    const float* xr = &s_cls[t * NC];
    float s0 = 0.f, s1 = 0.f, s2 = 0.f, s3 = 0.f;
    #pragma unroll
    for (int i = 0; i < 5; ++i) {
        float4 v;
        __builtin_memcpy(&v, (const char*)xr + 16 * i, 16);
        s0 += __expf(v.x); s1 += __expf(v.y);
        s2 += __expf(v.z); s3 += __expf(v.w);
    }
    s0 += __expf(xr[20]);
    const float lse    = __logf((s0 + s1) + (s2 + s3));
    const float ce_pos = lse - xr[lbl];
    const float ce_neg = lse - xr[0];

    // ---- smooth L1 vs matched box
    const float4 mb = s_tb4[bidx];
    float sl = 0.f;
    {
        const float d0 = rg.x - mb.x, d1 = rg.y - mb.y;
        const float d2 = rg.z - mb.z, d3 = rg.w - mb.w;
        const float e0 = fabsf(d0), e1 = fabsf(d1);
        const float e2 = fabsf(d2), e3 = fabsf(d3);
        sl += (e0 < 1.f) ? 0.5f * d0 * d0 : (e0 - 0.5f);
        sl += (e1 < 1.f) ? 0.5f * d1 * d1 : (e1 - 0.5f);
        sl += (e2 < 1.f) ? 0.5f * d2 * d2 : (e2 - 0.5f);
        sl += (e3 < 1.f) ? 0.5f * d3 * d3 : (e3 - 0.5f);
        sl *= 0.25f;
    }

    const float pm = (pos ? 1.f : 0.f) * msk;
    const float nm = (neg ? 1.f : 0.f) * msk;
    float v0 = pm * ce_pos, v2 = pm * sl, v3 = pm;
    float v1 = nm * ce_neg, v4 = nm;

    // block reduction: wave shuffle then across-wave LDS
    #pragma unroll
    for (int o = 32; o > 0; o >>= 1) {
        v0 += __shfl_down(v0, o);
        v1 += __shfl_down(v1, o);
        v2 += __shfl_down(v2, o);
        v3 += __shfl_down(v3, o);
        v4 += __shfl_down(v4, o);
    }
    const int wave = t >> 6;
    if ((t & 63) == 0) {
        s_red[wave][0] = v0; s_red[wave][1] = v1; s_red[wave][2] = v2;
        s_red[wave][3] = v3; s_red[wave][4] = v4;
    }
    __syncthreads();
    if (t == 0) {
        float r0 = 0, r1 = 0, r2 = 0, r3 = 0, r4 = 0;
        #pragma unroll
        for (int w = 0; w < TPB / 64; ++w) {
            r0 += s_red[w][0]; r1 += s_red[w][1]; r2 += s_red[w][2];
            r3 += s_red[w][3]; r4 += s_red[w][4];
        }
        float* q = partials + ((size_t)b * nblk + blk) * 5;
        q[0] = r0; q[1] = r1; q[2] = r2; q[3] = r3; q[4] = r4;
    }
}

// ---------------- finalize: wave-per-image, then batch combine ----------------
__global__ __launch_bounds__(512) void detloss_final(
    const float* __restrict__ partials, int nblk, int B, float* __restrict__ out)
{
    __shared__ float s_img[8][5];
    const int t    = threadIdx.x;
    const int b    = t >> 6;     // one wave per image
    const int lane = t & 63;

    if (b < B) {
        float v[5] = {0.f, 0.f, 0.f, 0.f, 0.f};
        for (int e = lane; e < nblk; e += 64) {
            const float* q = partials + ((size_t)b * nblk + e) * 5;
            #pragma unroll
            for (int k = 0; k < 5; ++k) v[k] += q[k];
        }
        #pragma unroll
        for (int o = 32; o > 0; o >>= 1) {
            #pragma unroll
            for (int k = 0; k < 5; ++k) v[k] += __shfl_down(v[k], o);
        }
        if (lane == 0) {
            const float npos = v[3], nneg = v[4];
            s_img[b][0] = v[0] / fmaxf(npos, 1.f);   // cls_loss_pos
            s_img[b][1] = v[1] / fmaxf(nneg, 1.f);   // cls_loss_neg
            s_img[b][2] = v[2] / fmaxf(npos, 1.f);   // reg_loss
            s_img[b][3] = (npos > 0.f) ? 1.f : 0.f;  // has_p
            s_img[b][4] = (nneg > 0.f) ? 1.f : 0.f;  // has_n
        }
    }
    __syncthreads();

    if (t == 0) {
        float cls_sum = 0.f, n_cls = 0.f, reg_sum = 0.f, n_reg = 0.f;
        for (int b2 = 0; b2 < B; ++b2) {
            cls_sum += s_img[b2][0] * s_img[b2][3] + s_img[b2][1] * s_img[b2][4];
            n_cls   += s_img[b2][3] + s_img[b2][4];
            reg_sum += s_img[b2][2] * s_img[b2][3];
            n_reg   += s_img[b2][3];
        }
        const float cls_mean = cls_sum / fmaxf(n_cls, 1.f);
        const float reg_mean = reg_sum / fmaxf(n_reg, 1.f);
        out[0] = ((n_cls > 0.f) ? cls_mean : 0.f) + ((n_reg > 0.f) ? reg_mean : 0.f);
    }
}

extern "C" void kernel_launch(void* const* d_in, const int* in_sizes, int n_in,
                              void* d_out, int out_size, void* d_ws, size_t ws_size,
                              hipStream_t stream) {
    const float* cls = (const float*)d_in[0];
    const float* reg = (const float*)d_in[1];
    const float* tbx = (const float*)d_in[2];
    const int*   tlb = (const int*)d_in[3];
    float*       out = (float*)d_out;
    float*  partials = (float*)d_ws;

    const int B = 8;
    const int N = in_sizes[1] / (B * 4);        // 131072
    const int nblk = (N + TPB - 1) / TPB;       // 512

    dim3 grid(nblk, B);
    detloss_main<<<grid, TPB, 0, stream>>>(cls, reg, tbx, tlb, partials, N, nblk);
    detloss_final<<<1, 512, 0, stream>>>(partials, nblk, B, out);
}

// Round 7
// 36.239 us; speedup vs baseline: 1.5345x; 1.5345x over previous
//
#include <hip/hip_runtime.h>
#include <math.h>

#define TPB 256
#define NC 21   // classes
#define NM 32   // targets per image
// per-wave LDS staging region: 64 rows * 21 floats = 1344 floats, padded to
// 1536 floats (6144 B) so the 6th DMA instruction's clamped lanes land in-region.
#define WREG 1536

// ---------------- main per-anchor kernel ----------------
__global__ __launch_bounds__(TPB) void detloss_main(
    const float* __restrict__ cls, const float* __restrict__ reg,
    const float* __restrict__ tbx, const int* __restrict__ tlb,
    float* __restrict__ partials, int N, int nblk)
{
    __shared__ float4 s_tb4[NM];
    __shared__ float  s_area2[NM];
    __shared__ int    s_tl[NM];
    __shared__ float  s_cls[4 * WREG];   // 24576 B, wave-private quarters
    __shared__ float  s_red[TPB / 64][5];

    const int t    = threadIdx.x;
    const int lane = t & 63;
    const int w    = t >> 6;
    const int blk  = blockIdx.x;
    const int b    = blockIdx.y;
    const int row0 = blk * TPB;
    const int row  = row0 + t;

    // targets: one thread per target box
    if (t < NM) {
        const float4 tb = ((const float4*)tbx)[(size_t)b * NM + t];
        s_tb4[t]   = tb;
        s_area2[t] = (tb.z - tb.x) * (tb.w - tb.y);
        s_tl[t]    = tlb[(size_t)b * NM + t];
    }
    __syncthreads();   // targets ready; only tiny loads drained here

    // per-thread anchor box (coalesced float4), clamped
    const int   rowi = (row < N) ? row : (N - 1);
    const float msk  = (row < N) ? 1.f : 0.f;
    const float4 rg  = ((const float4*)reg)[(size_t)b * N + rowi];

    // ---- wave-private DMA staging of this wave's 64 cls rows.
    // global_load_lds: zero VGPR round-trip (R6's spill trap avoided), global
    // side fully coalesced (1KB/instr -> no L1 line amplification), LDS dest
    // linear (uniform base + lane*16). No block barrier: each wave owns its
    // region and waits only its own vmcnt.
    const bool fast = ((N & 63) == 0) && (row0 + TPB <= N);
    const int  wrow0 = row0 + w * 64;
    const float* wbase = cls + ((size_t)b * N + wrow0) * NC;   // 16B-aligned
    float* lbase = &s_cls[w * WREG];                           // wave-uniform
    if (fast) {
        #pragma unroll
        for (int r = 0; r < 6; ++r) {
            const int slot = min(r * 64 + lane, 335);          // 336 real slots
            __builtin_amdgcn_global_load_lds(
                (const __attribute__((address_space(1))) void*)
                    ((const char*)wbase + (size_t)slot * 16),
                (__attribute__((address_space(3))) void*)
                    ((char*)lbase + r * 1024),
                16, 0, 0);
        }
    }

    // ---- divide-free argmax-IoU (pure VALU; hides the DMA latency).
    // unions strictly positive -> iou_j > iou_best <=> inter*bu > bi*uni
    const float a1 = (rg.z - rg.x) * (rg.w - rg.y);
    float bi, bu; int bidx = 0;
    {
        const float4 tb = s_tb4[0];
        const float lx = fmaxf(rg.x, tb.x), ly = fmaxf(rg.y, tb.y);
        const float rx = fminf(rg.z, tb.z), ry = fminf(rg.w, tb.w);
        const float wd = fmaxf(rx - lx, 0.f), h = fmaxf(ry - ly, 0.f);
        bi = wd * h;
        bu = a1 + s_area2[0] - bi;
    }
    #pragma unroll
    for (int j = 1; j < NM; ++j) {
        const float4 tb = s_tb4[j];
        const float lx = fmaxf(rg.x, tb.x), ly = fmaxf(rg.y, tb.y);
        const float rx = fminf(rg.z, tb.z), ry = fminf(rg.w, tb.w);
        const float wd = fmaxf(rx - lx, 0.f), h = fmaxf(ry - ly, 0.f);
        const float inter = wd * h;
        const float uni   = a1 + s_area2[j] - inter;
        const bool  gt    = inter * bu > bi * uni;   // strict > == first argmax
        bi   = gt ? inter : bi;
        bu   = gt ? uni   : bu;
        bidx = gt ? j     : bidx;
    }
    const bool pos = (bi >= 0.5f * bu);
    const bool neg = (bi <  0.3f * bu);
    const int  lbl = s_tl[bidx];

    // ---- log-sum-exp. Native trans, no max-subtract (inputs ~N(0,1)).
    float s0 = 0.f, s1 = 0.f, s2 = 0.f, s3 = 0.f, x0, xlbl;
    if (fast) {
        asm volatile("s_waitcnt vmcnt(0)" ::: "memory");  // this wave's DMA done
        const float* xr = lbase + lane * NC;  // stride-21 dwords: 2-way max = free
        #pragma unroll
        for (int c = 0; c < 20; c += 4) {
            s0 += __expf(xr[c]);     s1 += __expf(xr[c + 1]);
            s2 += __expf(xr[c + 2]); s3 += __expf(xr[c + 3]);
        }
        s0 += __expf(xr[20]);
        x0   = xr[0];
        xlbl = xr[lbl];              // single dynamic LDS read
    } else {
        // tail fallback: streamed direct reads (R4 path)
        const char* xg = (const char*)(cls + ((size_t)b * N + rowi) * NC);
        x0 = 0.f; xlbl = 0.f;
        #pragma unroll
        for (int i = 0; i < 5; ++i) {
            float4 v;
            __builtin_memcpy(&v, xg + 16 * i, 16);
            s0 += __expf(v.x); s1 += __expf(v.y);
            s2 += __expf(v.z); s3 += __expf(v.w);
            if (i == 0) x0 = v.x;
            const int base = 4 * i;
            const float sel = (lbl == base    ) ? v.x :
                              (lbl == base + 1) ? v.y :
                              (lbl == base + 2) ? v.z : v.w;
            xlbl = (lbl >= base && lbl <= base + 3) ? sel : xlbl;
        }
        float xt;
        __builtin_memcpy(&xt, xg + 80, 4);
        s0 += __expf(xt);
        xlbl = (lbl == 20) ? xt : xlbl;
    }
    const float lse    = __logf((s0 + s1) + (s2 + s3));
    const float ce_pos = lse - xlbl;
    const float ce_neg = lse - x0;

    // ---- smooth L1 vs matched box
    const float4 mb = s_tb4[bidx];
    float sl = 0.f;
    {
        const float d0 = rg.x - mb.x, d1 = rg.y - mb.y;
        const float d2 = rg.z - mb.z, d3 = rg.w - mb.w;
        const float e0 = fabsf(d0), e1 = fabsf(d1);
        const float e2 = fabsf(d2), e3 = fabsf(d3);
        sl += (e0 < 1.f) ? 0.5f * d0 * d0 : (e0 - 0.5f);
        sl += (e1 < 1.f) ? 0.5f * d1 * d1 : (e1 - 0.5f);
        sl += (e2 < 1.f) ? 0.5f * d2 * d2 : (e2 - 0.5f);
        sl += (e3 < 1.f) ? 0.5f * d3 * d3 : (e3 - 0.5f);
        sl *= 0.25f;
    }

    const float pm = (pos ? 1.f : 0.f) * msk;
    const float nm = (neg ? 1.f : 0.f) * msk;
    float v0 = pm * ce_pos, v2 = pm * sl, v3 = pm;
    float v1 = nm * ce_neg, v4 = nm;

    // block reduction: wave shuffle then across-wave LDS
    #pragma unroll
    for (int o = 32; o > 0; o >>= 1) {
        v0 += __shfl_down(v0, o);
        v1 += __shfl_down(v1, o);
        v2 += __shfl_down(v2, o);
        v3 += __shfl_down(v3, o);
        v4 += __shfl_down(v4, o);
    }
    if (lane == 0) {
        s_red[w][0] = v0; s_red[w][1] = v1; s_red[w][2] = v2;
        s_red[w][3] = v3; s_red[w][4] = v4;
    }
    __syncthreads();
    if (t == 0) {
        float r0 = 0, r1 = 0, r2 = 0, r3 = 0, r4 = 0;
        #pragma unroll
        for (int k = 0; k < TPB / 64; ++k) {
            r0 += s_red[k][0]; r1 += s_red[k][1]; r2 += s_red[k][2];
            r3 += s_red[k][3]; r4 += s_red[k][4];
        }
        float* q = partials + ((size_t)b * nblk + blk) * 5;
        q[0] = r0; q[1] = r1; q[2] = r2; q[3] = r3; q[4] = r4;
    }
}

// ---------------- finalize: wave-per-image, then batch combine ----------------
__global__ __launch_bounds__(512) void detloss_final(
    const float* __restrict__ partials, int nblk, int B, float* __restrict__ out)
{
    __shared__ float s_img[8][5];
    const int t    = threadIdx.x;
    const int b    = t >> 6;     // one wave per image
    const int lane = t & 63;

    if (b < B) {
        float v[5] = {0.f, 0.f, 0.f, 0.f, 0.f};
        for (int e = lane; e < nblk; e += 64) {
            const float* q = partials + ((size_t)b * nblk + e) * 5;
            #pragma unroll
            for (int k = 0; k < 5; ++k) v[k] += q[k];
        }
        #pragma unroll
        for (int o = 32; o > 0; o >>= 1) {
            #pragma unroll
            for (int k = 0; k < 5; ++k) v[k] += __shfl_down(v[k], o);
        }
        if (lane == 0) {
            const float npos = v[3], nneg = v[4];
            s_img[b][0] = v[0] / fmaxf(npos, 1.f);   // cls_loss_pos
            s_img[b][1] = v[1] / fmaxf(nneg, 1.f);   // cls_loss_neg
            s_img[b][2] = v[2] / fmaxf(npos, 1.f);   // reg_loss
            s_img[b][3] = (npos > 0.f) ? 1.f : 0.f;  // has_p
            s_img[b][4] = (nneg > 0.f) ? 1.f : 0.f;  // has_n
        }
    }
    __syncthreads();

    if (t == 0) {
        float cls_sum = 0.f, n_cls = 0.f, reg_sum = 0.f, n_reg = 0.f;
        for (int b2 = 0; b2 < B; ++b2) {
            cls_sum += s_img[b2][0] * s_img[b2][3] + s_img[b2][1] * s_img[b2][4];
            n_cls   += s_img[b2][3] + s_img[b2][4];
            reg_sum += s_img[b2][2] * s_img[b2][3];
            n_reg   += s_img[b2][3];
        }
        const float cls_mean = cls_sum / fmaxf(n_cls, 1.f);
        const float reg_mean = reg_sum / fmaxf(n_reg, 1.f);
        out[0] = ((n_cls > 0.f) ? cls_mean : 0.f) + ((n_reg > 0.f) ? reg_mean : 0.f);
    }
}

extern "C" void kernel_launch(void* const* d_in, const int* in_sizes, int n_in,
                              void* d_out, int out_size, void* d_ws, size_t ws_size,
                              hipStream_t stream) {
    const float* cls = (const float*)d_in[0];
    const float* reg = (const float*)d_in[1];
    const float* tbx = (const float*)d_in[2];
    const int*   tlb = (const int*)d_in[3];
    float*       out = (float*)d_out;
    float*  partials = (float*)d_ws;

    const int B = 8;
    const int N = in_sizes[1] / (B * 4);        // 131072
    const int nblk = (N + TPB - 1) / TPB;       // 512

    dim3 grid(nblk, B);
    detloss_main<<<grid, TPB, 0, stream>>>(cls, reg, tbx, tlb, partials, N, nblk);
    detloss_final<<<1, 512, 0, stream>>>(partials, nblk, B, out);
}